// Round 5
// baseline (313.044 us; speedup 1.0000x reference)
//
#include <hip/hip_runtime.h>

#define M1 81
#define MSZ 80
#define NEL (M1 * M1)          // 6561
#define NACC 12
#define BIGKC 1.0e30f

// accumulator indices:
// 0 target_num, 1 n_pre, 2 n_next, 3 n_union,
// 4 s_pre, 5 s_next, 6 s_all, 7 s_sim,
// 8 s_acc_pre, 9 s_acc_next, 10 n_mpre, 11 n_mnext

// Quarter ranges over 81 elements: q0:[0,21) q1:[21,41) q2:[41,61) q3:[61,81)
// (K2 peels index 80 out of q3). Quads (4 consecutive threads) are wave-aligned.

__device__ __forceinline__ void block_reduce_write(
    float* a, float* part, int nbTot, int slot)
{
    __shared__ float s_wv[4][NACC];
    const int tid = threadIdx.x;
    const int lane = tid & 63, w = tid >> 6;
#pragma unroll
    for (int k = 0; k < NACC; ++k) {
        float v = a[k];
        for (int off = 32; off > 0; off >>= 1) v += __shfl_down(v, off);
        if (lane == 0) s_wv[w][k] = v;
    }
    __syncthreads();
    if (tid < NACC) {
        part[tid * nbTot + slot] =
            s_wv[0][tid] + s_wv[1][tid] + s_wv[2][tid] + s_wv[3][tid];
    }
}

// K1: row denominators (first rowBlocks blocks) + column stats (rest).
__global__ __launch_bounds__(256) void sst_stats(
    const float* __restrict__ input,
    const int* __restrict__ target,
    const int* __restrict__ mask0,
    const int* __restrict__ mask1,
    float2* __restrict__ rowc,      // {lr, 1/rsum} per (slice,row)
    float4* __restrict__ colc,      // {m1c, kc, 1/csum, 0} per (slice,col)
    float* __restrict__ part, int nbTot, int slices, int rowBlocks)
{
    const int tid = threadIdx.x;
    float a[NACC];
#pragma unroll
    for (int k = 0; k < NACC; ++k) a[k] = 0.0f;

    if ((int)blockIdx.x < rowBlocks) {
        // ---------- row task: rsum only ----------
        const int t = blockIdx.x * 256 + tid;
        if (t < slices * 324) {
            const int slice = t / 324;
            const int rem = t - slice * 324;
            const int r = rem >> 2;
            const int q = rem & 3;
            const int mbase = slice * M1;
            if (r == MSZ) {
                // pre-mask zeroes row 80 -> rsum = 81 exactly
                if (q == 0) rowc[mbase + r] = make_float2(__logf(81.0f), 1.0f / 81.0f);
            } else {
                const float m0 = (float)mask0[mbase + r];
                const size_t rb = (size_t)slice * NEL + (size_t)r * M1;
                const int c0 = (q == 0) ? 0 : (20 * q + 1);
                const int c1 = (q == 3) ? M1 : ((q == 0) ? 21 : c0 + 20);
                float s = 0.0f;
                for (int c = c0; c < c1; ++c) {
                    const float m1c = (float)mask1[mbase + c];
                    s += __expf(m0 * m1c * input[rb + c]);
                }
                s += __shfl_xor(s, 1);   // (q0+q1),(q2+q3)
                s += __shfl_xor(s, 2);   // total
                if (q == 0) rowc[mbase + r] = make_float2(__logf(s), 1.0f / s);
            }
        }
        return;  // row blocks write no partials
    }

    // ---------- col task: csum + argmax + first-target + accuracy_next ----------
    const int t = (blockIdx.x - rowBlocks) * 256 + tid;
    if (t < slices * 324) {
        const int slice = t / 324;
        const int rem = t - slice * 324;
        const int c = rem >> 2;
        const int q = rem & 3;
        const int mbase = slice * M1;
        if (c == MSZ) {
            // next-mask zeroes col 80 -> csum = 81; kc sentinel makes min(lr,kc)=lr
            if (q == 0) colc[mbase + c] =
                make_float4((float)mask1[mbase + c], BIGKC, 1.0f / 81.0f, 0.0f);
        } else {
            const float m1c = (float)mask1[mbase + c];
            const size_t sb = (size_t)slice * NEL;
            const int r0 = (q == 0) ? 0 : (20 * q + 1);
            const int r1 = (q == 0) ? 21 : (r0 + 20);     // q3: 61..81
            float cs = 0.0f, bv = -1.0f;
            int bi = r0, ct = 127;
            for (int r = r0; r < r1; ++r) {
                const float m0r = (float)mask0[mbase + r];
                const float mn = m1c * m0r;
                const float e = __expf(mn * input[sb + (size_t)r * M1 + c]);
                cs += e;
                if (e > bv) { bv = e; bi = r; }            // first-max within quarter
                if (ct == 127 && mn != 0.0f && target[sb + (size_t)r * M1 + c] != 0) ct = r;
            }
            // deterministic quad merge (ascending r; bi compare = first-max)
            cs += __shfl_xor(cs, 1);
            cs += __shfl_xor(cs, 2);
            float ov = __shfl_xor(bv, 1); int oi = __shfl_xor(bi, 1); int ot = __shfl_xor(ct, 1);
            if (ov > bv || (ov == bv && oi < bi)) { bv = ov; bi = oi; }
            ct = min(ct, ot);
            ov = __shfl_xor(bv, 2); oi = __shfl_xor(bi, 2); ot = __shfl_xor(ct, 2);
            if (ov > bv || (ov == bv && oi < bi)) { bv = ov; bi = oi; }
            ct = min(ct, ot);
            if (q == 0) {
                colc[mbase + c] = make_float4(m1c, __logf(cs), 1.0f / cs, 0.0f);
                const int ti = (ct == 127) ? 0 : ct;
                a[9]  += (bi == ti) ? m1c : 0.0f;
                a[11] += m1c;
            }
        }
    }
    block_reduce_write(a, part, nbTot, blockIdx.x - rowBlocks);
}

// K2: per-element sums + row argmax / accuracy_pre. 4 threads per row.
__global__ __launch_bounds__(256) void sst_elem(
    const float* __restrict__ input,
    const int* __restrict__ target,
    const int* __restrict__ mask0,
    const float2* __restrict__ rowc,
    const float4* __restrict__ colc,
    float* __restrict__ out_idx,    // d_out + 7
    float* __restrict__ part, int nbTot, int partBase, int slices)
{
    const int tid = threadIdx.x;
    float a[NACC];
#pragma unroll
    for (int k = 0; k < NACC; ++k) a[k] = 0.0f;

    const int t = blockIdx.x * 256 + tid;
    if (t < slices * 324) {
        const int slice = t / 324;
        const int rem = t - slice * 324;
        const int r = rem >> 2;
        const int q = rem & 3;
        const int mbase = slice * M1;
        const size_t rb = (size_t)slice * NEL + (size_t)r * M1;
        const float m0f = (float)mask0[mbase + r];
        const float m0p = (r == MSZ) ? 0.0f : m0f;
        const float2 rw = rowc[mbase + r];
        const float lr = rw.x, invr = rw.y;
        const int c0 = (q == 0) ? 0 : (20 * q + 1);
        const int c1 = (q == 3) ? MSZ : ((q == 0) ? 21 : c0 + 20);
        float bv = -3.402823466e38f;
        int bi = c0, ti = 127;
        for (int c = c0; c < c1; ++c) {
            const float4 cc = colc[mbase + c];
            const float m1c = cc.x, kc = cc.y, invc = cc.z;
            const float x = input[rb + c];
            const float tf = (target[rb + c] != 0) ? 1.0f : 0.0f;
            const float mf = m0f * m1c;     // mask_region (== mnext for c<80)
            const float z  = mf * x;
            const float mp = m0p * m1c;     // mask_region_pre
            const float tp = tf * mp;       // target_pre (== target_union here)
            const float tn = tf * mf;       // target_next
            a[0] += tf; a[1] += tp; a[2] += tn; a[3] += tp;
            a[4] = fmaf(tp, lr - z, a[4]);
            a[5] = fmaf(tn, kc - z, a[5]);
            const float mlk = fminf(lr, kc);
            a[6] = fmaf(tp, mlk - z, a[6]);
            const float e = __expf(z);
            a[7] = fmaf(tp * e, fabsf(invc - invr), a[7]);
            const float val = z - mlk;      // log input_all (monotone)
            if (val > bv) { bv = val; bi = c; }
            if (ti == 127 && tp != 0.0f) ti = c;
        }
        if (q == 3) {  // peel c = 80: input_all = input_pre; no next/union terms
            const float4 cc = colc[mbase + MSZ];
            const float m1c = cc.x;
            const float x = input[rb + MSZ];
            const float tf = (target[rb + MSZ] != 0) ? 1.0f : 0.0f;
            const float z  = m0f * m1c * x;     // == mp*x for r<80; tp=0 for r=80
            const float tp = tf * (m0p * m1c);
            a[0] += tf; a[1] += tp;
            a[4] = fmaf(tp, lr - z, a[4]);
            a[6] = fmaf(tp, lr - z, a[6]);
            const float val = z - lr;
            if (val > bv) { bv = val; bi = MSZ; }
            if (ti == 127 && tp != 0.0f) ti = MSZ;
        }
        // deterministic quad merge (ascending c; bi compare = first-max)
        float ov = __shfl_xor(bv, 1); int oi = __shfl_xor(bi, 1); int ot = __shfl_xor(ti, 1);
        if (ov > bv || (ov == bv && oi < bi)) { bv = ov; bi = oi; }
        ti = min(ti, ot);
        ov = __shfl_xor(bv, 2); oi = __shfl_xor(bi, 2); ot = __shfl_xor(ti, 2);
        if (ov > bv || (ov == bv && oi < bi)) { bv = ov; bi = oi; }
        ti = min(ti, ot);
        if (q == 0 && r < MSZ) {
            out_idx[(size_t)slice * MSZ + r] = (float)bi;
            const int tm = (ti == 127) ? 0 : ti;
            a[8]  += (bi == tm) ? m0f : 0.0f;
            a[10] += m0f;
        }
    }
    block_reduce_write(a, part, nbTot, partBase + blockIdx.x);
}

__global__ __launch_bounds__(256) void sst_final(
    const float* __restrict__ part, int nbTot, float* __restrict__ out)
{
    __shared__ double s_part[4][NACC];
    const int tid = threadIdx.x;
    double l[NACC];
#pragma unroll
    for (int k = 0; k < NACC; ++k) l[k] = 0.0;
    for (int s = tid; s < nbTot; s += 256) {
#pragma unroll
        for (int k = 0; k < NACC; ++k) l[k] += (double)part[(size_t)k * nbTot + s];
    }
#pragma unroll
    for (int k = 0; k < NACC; ++k) {
        double v = l[k];
        for (int off = 32; off > 0; off >>= 1) v += __shfl_down(v, off);
        if ((tid & 63) == 0) s_part[tid >> 6][k] = v;
    }
    __syncthreads();
    if (tid == 0) {
        double g[NACC];
#pragma unroll
        for (int k = 0; k < NACC; ++k)
            g[k] = s_part[0][k] + s_part[1][k] + s_part[2][k] + s_part[3][k];
        const double tnum = g[0], npre = g[1], nnext = g[2], nunion = g[3];
        const double spre = g[4], snext = g[5], sall = g[6], ssim = g[7];
        const double accp = g[8], accn = g[9], nmp = g[10], nmn = g[11];
        const double loss_pre  = (npre > 0.0) ? spre / npre : spre;
        const double loss_next = (nnext > 0.0) ? snext / nnext : snext;
        const double loss      = (npre > 0.0 && nnext > 0.0) ? sall / npre : sall;
        const double loss_sim  = (nunion > 0.0) ? ssim / tnum : ssim;
        const double total = (loss_pre + loss_next + loss + loss_sim) * 0.25;
        const double ap = (nmp > 0.0) ? accp / nmp : accp + 1.0;
        const double an = (nmn > 0.0) ? accn / nmn : accn + 1.0;
        out[0] = (float)loss_pre;
        out[1] = (float)loss_next;
        out[2] = (float)loss_sim;
        out[3] = (float)total;
        out[4] = (float)ap;
        out[5] = (float)an;
        out[6] = (float)((ap + an) * 0.5);
    }
}

extern "C" void kernel_launch(void* const* d_in, const int* in_sizes, int n_in,
                              void* d_out, int out_size, void* d_ws, size_t ws_size,
                              hipStream_t stream) {
    const float* input  = (const float*)d_in[0];
    const int*   target = (const int*)d_in[1];
    const int*   mask0  = (const int*)d_in[2];
    const int*   mask1  = (const int*)d_in[3];
    float* out = (float*)d_out;

    const int slices = in_sizes[0] / NEL;          // B*C = 2048
    const int qBlocks = (slices * 324 + 255) / 256; // 2592 (quads never split)
    const int k1Blocks = qBlocks * 2;               // rows + cols
    const int nbTot = qBlocks * 2;                  // partial slots: cols + K2

    // workspace layout (≈4.4 MB): colc | rowc | part
    float4* colc = (float4*)d_ws;                           // slices*81
    float2* rowc = (float2*)(colc + (size_t)slices * M1);   // slices*81
    float*  part = (float*)(rowc + (size_t)slices * M1);    // NACC*nbTot

    sst_stats<<<k1Blocks, 256, 0, stream>>>(input, target, mask0, mask1,
                                            rowc, colc, part, nbTot, slices, qBlocks);
    sst_elem<<<qBlocks, 256, 0, stream>>>(input, target, mask0,
                                          rowc, colc, out + 7, part, nbTot, qBlocks, slices);
    sst_final<<<1, 256, 0, stream>>>(part, nbTot, out);
}

// Round 6
// 170.188 us; speedup vs baseline: 1.8394x; 1.8394x over previous
//
#include <hip/hip_runtime.h>

#define M1 81
#define MSZ 80
#define NEL (M1 * M1)          // 6561
#define NTW ((NEL + 31) / 32)  // 206 words of target bits
#define NACC 12
#define BIGKC 1.0e30f
#define LOG81 4.394449154672439f
#define INV81 0.012345679012345678f

// accumulator indices:
// 0 target_num, 1 n_pre, 2 n_next, 3 n_union,
// 4 s_pre, 5 s_next, 6 s_all, 7 s_sim,
// 8 s_acc_pre, 9 s_acc_next, 10 n_mpre, 11 n_mnext

__device__ __forceinline__ float tbitf(const unsigned* tb, int idx) {
    return (float)((tb[idx >> 5] >> (idx & 31)) & 1u);
}

__global__ __launch_bounds__(512, 8) void sst_main(
    const float* __restrict__ input,
    const int* __restrict__ target,
    const int* __restrict__ mask0,
    const int* __restrict__ mask1,
    float* __restrict__ out_idx,   // d_out + 7, [slices*80] floats
    float* __restrict__ part,      // SoA: part[k*slices + slice]
    int slices)
{
    __shared__ float s_x[NEL];
    __shared__ unsigned s_tb[NTW];
    __shared__ float s_m0[M1], s_m1[M1];
    __shared__ float2 s_rowc[M1];      // {lr, 1/rsum}
    __shared__ float4 s_colc[M1];      // {m1c, kc (1e30 @80), 1/csum, 0}
    __shared__ float s_pA[486];        // rs / cs partials
    __shared__ float s_pB[486];        // St / Sn partials
    __shared__ float s_pV[486];        // argmax value partials
    __shared__ unsigned char s_pI[486];// argmax index partials
    __shared__ unsigned char s_pT[486];// first-target partials (127 = none)
    __shared__ unsigned char s_ti[M1]; // merged row first-target col
    __shared__ float s_wv[8][NACC];

    const int tid   = threadIdx.x;
    const int lane  = tid & 63;
    const int w     = tid >> 6;
    const int slice = blockIdx.x;
    const size_t base = (size_t)slice * NEL;

    if (tid < M1) s_m0[tid] = (float)mask0[slice * M1 + tid];
    else if (tid >= 128 && tid < 128 + M1) s_m1[tid - 128] = (float)mask1[slice * M1 + (tid - 128)];

    float a[NACC];
#pragma unroll
    for (int k = 0; k < NACC; ++k) a[k] = 0.0f;

    // ---- staging: coalesced input + ballot-packed target bits + target_num ----
    for (int i = tid; i < NEL; i += 512) {
        s_x[i] = input[base + i];
        const int tv = target[base + i];
        a[0] += (tv != 0) ? 1.0f : 0.0f;
        unsigned long long m = __ballot(tv != 0);
        if (lane == 0) {
            const int w2 = (i >> 5) & ~1;
            s_tb[w2] = (unsigned)m;
            if (w2 + 1 < NTW) s_tb[w2 + 1] = (unsigned)(m >> 32);
        }
    }
    __syncthreads();   // B1

    // ---- pass 1: 3-thread teams. rows on tid 0..242, cols on tid 256..498 ----
    if (tid < 243) {
        const int r = tid / 3, j = tid - 3 * (tid / 3);
        if (r < MSZ) {
            const float m0p = s_m0[r];
            const int rb = r * M1;
            const int c0 = 27 * j;
            float rs = 0.0f, St = 0.0f, Sz = 0.0f;
            int ti = 127;
            for (int c = c0; c < c0 + 27; ++c) {
                const float m1c = s_m1[c];
                const float x = s_x[rb + c];
                const float mp = m0p * m1c;
                const float z = mp * x;
                rs += __expf(z);
                const float tf = tbitf(s_tb, rb + c);
                const float tp = tf * mp;
                a[1] += tp;
                a[3] += (c < MSZ) ? tp : 0.0f;
                Sz = fmaf(tp, z, Sz);
                St += tp;
                if (ti == 127 && tp != 0.0f) ti = c;
            }
            a[4] -= Sz;            // -sum tp*z  (s_pre linear part)
            a[6] -= Sz;            // same term appears in s_all
            s_pA[tid] = rs;
            s_pB[tid] = St;
            s_pT[tid] = (unsigned char)ti;
        }
        // r == 80: handled at merge (rsum = 81 exactly)
    } else if (tid >= 256 && tid < 499) {
        const int u = tid - 256;
        const int c = u / 3, j = u - 3 * (u / 3);
        if (c < MSZ) {
            const float m1n = s_m1[c];
            const int r0 = 27 * j;
            float cs = 0.0f, Sn = 0.0f, Sz = 0.0f, bv = -1.0f;
            int bi = r0, ct = 127;
            for (int r = r0; r < r0 + 27; ++r) {
                const float mn = m1n * s_m0[r];
                const float x = s_x[r * M1 + c];
                const float z = mn * x;
                const float e = __expf(z);
                cs += e;
                if (e > bv) { bv = e; bi = r; }   // first-max within chunk
                const float tf = tbitf(s_tb, r * M1 + c);
                const float tn = tf * mn;
                a[2] += tn;
                Sz = fmaf(tn, z, Sz);
                Sn += tn;
                if (ct == 127 && tn != 0.0f) ct = r;
            }
            a[5] -= Sz;            // -sum tn*z  (s_next linear part)
            s_pA[243 + u] = cs;
            s_pB[243 + u] = Sn;
            s_pV[243 + u] = bv;
            s_pI[243 + u] = (unsigned char)bi;
            s_pT[243 + u] = (unsigned char)ct;
        }
        // c == 80: handled at merge (sentinel)
    }
    __syncthreads();   // B2

    // ---- merge: rowc on tid<81, colc + accuracy_next on tid 128..208 ----
    if (tid < M1) {
        const int r = tid;
        if (r < MSZ) {
            const int b = 3 * r;
            const float rs = s_pA[b] + s_pA[b + 1] + s_pA[b + 2];
            const float lr = __logf(rs);
            s_rowc[r] = make_float2(lr, 1.0f / rs);
            const float St = s_pB[b] + s_pB[b + 1] + s_pB[b + 2];
            a[4] = fmaf(St, lr, a[4]);
            int ti = min(min((int)s_pT[b], (int)s_pT[b + 1]), (int)s_pT[b + 2]);
            s_ti[r] = (unsigned char)((ti == 127) ? 0 : ti);
        } else {
            s_rowc[r] = make_float2(LOG81, INV81);
            s_ti[r] = 0;
        }
    } else if (tid >= 128 && tid < 128 + M1) {
        const int c = tid - 128;
        if (c < MSZ) {
            const int b = 243 + 3 * c;
            const float cs = s_pA[b] + s_pA[b + 1] + s_pA[b + 2];
            const float kc = __logf(cs);
            const float m1c = s_m1[c];
            s_colc[c] = make_float4(m1c, kc, 1.0f / cs, 0.0f);
            const float Sn = s_pB[b] + s_pB[b + 1] + s_pB[b + 2];
            a[5] = fmaf(Sn, kc, a[5]);
            float bv = s_pV[b]; int bi = s_pI[b];
            const float v1 = s_pV[b + 1]; if (v1 > bv) { bv = v1; bi = s_pI[b + 1]; }
            const float v2 = s_pV[b + 2]; if (v2 > bv) { bv = v2; bi = s_pI[b + 2]; }
            int ct = min(min((int)s_pT[b], (int)s_pT[b + 1]), (int)s_pT[b + 2]);
            if (ct == 127) ct = 0;
            a[9]  += (bi == ct) ? m1c : 0.0f;
            a[11] += m1c;
        } else {
            s_colc[c] = make_float4(s_m1[c], BIGKC, INV81, 0.0f);
        }
    }
    __syncthreads();   // B3

    // ---- pass 2: non-separable terms + row argmax. 6-thread teams, 486 active ----
    if (tid < 486) {
        const int r = tid / 6, j2 = tid - 6 * (tid / 6);
        const int c0 = j2 * 13 + ((j2 < 3) ? j2 : 3);
        const int c1 = c0 + ((j2 < 3) ? 14 : 13);
        const int rb = r * M1;
        const float m0f = s_m0[r];
        const float m0p = (r == MSZ) ? 0.0f : m0f;
        const float2 rw = s_rowc[r];
        const float lr = rw.x, invr = rw.y;
        float bv = -3.402823466e38f;
        int bi = c0;
        for (int c = c0; c < c1; ++c) {
            const float4 cc = s_colc[c];
            const float m1c = cc.x, kc = cc.y, invc = cc.z;
            const float x = s_x[rb + c];
            const float tf = tbitf(s_tb, rb + c);
            const float mf = m0f * m1c;
            const float z = mf * x;
            const float mlk = fminf(lr, kc);        // c=80: kc=1e30 -> mlk=lr
            const float mp = m0p * m1c;
            const float tp = tf * mp;
            a[6] = fmaf(tp, mlk, a[6]);             // +tp*mlk (z part done in pass 1)
            const float e = __expf(z);
            const float t7 = (c < MSZ) ? tp : 0.0f; // union excludes col 80
            a[7] = fmaf(t7 * e, fabsf(invc - invr), a[7]);
            const float val = z - mlk;              // log input_all (monotone)
            if (val > bv) { bv = val; bi = c; }
        }
        s_pV[tid] = bv;
        s_pI[tid] = (unsigned char)bi;
    }
    __syncthreads();   // B4

    if (tid < MSZ) {   // merge row argmax (ascending chunks, strict >: first-max)
        const int r = tid, b = 6 * r;
        float bv = s_pV[b]; int bi = s_pI[b];
#pragma unroll
        for (int k = 1; k < 6; ++k) {
            const float v = s_pV[b + k];
            if (v > bv) { bv = v; bi = s_pI[b + k]; }
        }
        out_idx[(size_t)slice * MSZ + r] = (float)bi;
        const float m0f = s_m0[r];
        a[8]  += (bi == (int)s_ti[r]) ? m0f : 0.0f;
        a[10] += m0f;
    }

    // ---- block reduce: wave shuffle -> LDS -> SoA partials ----
#pragma unroll
    for (int k = 0; k < NACC; ++k) {
        float v = a[k];
        for (int off = 32; off > 0; off >>= 1) v += __shfl_down(v, off);
        if (lane == 0) s_wv[w][k] = v;
    }
    __syncthreads();   // B5
    if (tid < NACC) {
        float s = 0.0f;
#pragma unroll
        for (int ww = 0; ww < 8; ++ww) s += s_wv[ww][tid];
        part[(size_t)tid * slices + slice] = s;
    }
}

__global__ __launch_bounds__(256) void sst_final(
    const float* __restrict__ part, int slices, float* __restrict__ out)
{
    __shared__ double s_part[4][NACC];
    const int tid = threadIdx.x;
    double l[NACC];
#pragma unroll
    for (int k = 0; k < NACC; ++k) l[k] = 0.0;
    for (int s = tid; s < slices; s += 256) {
#pragma unroll
        for (int k = 0; k < NACC; ++k) l[k] += (double)part[(size_t)k * slices + s];
    }
#pragma unroll
    for (int k = 0; k < NACC; ++k) {
        double v = l[k];
        for (int off = 32; off > 0; off >>= 1) v += __shfl_down(v, off);
        if ((tid & 63) == 0) s_part[tid >> 6][k] = v;
    }
    __syncthreads();
    if (tid == 0) {
        double g[NACC];
#pragma unroll
        for (int k = 0; k < NACC; ++k)
            g[k] = s_part[0][k] + s_part[1][k] + s_part[2][k] + s_part[3][k];
        const double tnum = g[0], npre = g[1], nnext = g[2], nunion = g[3];
        const double spre = g[4], snext = g[5], sall = g[6], ssim = g[7];
        const double accp = g[8], accn = g[9], nmp = g[10], nmn = g[11];
        const double loss_pre  = (npre > 0.0) ? spre / npre : spre;
        const double loss_next = (nnext > 0.0) ? snext / nnext : snext;
        const double loss      = (npre > 0.0 && nnext > 0.0) ? sall / npre : sall;
        const double loss_sim  = (nunion > 0.0) ? ssim / tnum : ssim;
        const double total = (loss_pre + loss_next + loss + loss_sim) * 0.25;
        const double ap = (nmp > 0.0) ? accp / nmp : accp + 1.0;
        const double an = (nmn > 0.0) ? accn / nmn : accn + 1.0;
        out[0] = (float)loss_pre;
        out[1] = (float)loss_next;
        out[2] = (float)loss_sim;
        out[3] = (float)total;
        out[4] = (float)ap;
        out[5] = (float)an;
        out[6] = (float)((ap + an) * 0.5);
    }
}

extern "C" void kernel_launch(void* const* d_in, const int* in_sizes, int n_in,
                              void* d_out, int out_size, void* d_ws, size_t ws_size,
                              hipStream_t stream) {
    const float* input  = (const float*)d_in[0];
    const int*   target = (const int*)d_in[1];
    const int*   mask0  = (const int*)d_in[2];
    const int*   mask1  = (const int*)d_in[3];
    float* out = (float*)d_out;
    float* part = (float*)d_ws;   // NACC * slices floats, SoA

    const int slices = in_sizes[0] / NEL;  // B*C = 2048

    sst_main<<<slices, 512, 0, stream>>>(input, target, mask0, mask1, out + 7, part, slices);
    sst_final<<<1, 256, 0, stream>>>(part, slices, out);
}

// Round 7
// 166.753 us; speedup vs baseline: 1.8773x; 1.0206x over previous
//
#include <hip/hip_runtime.h>

#define M1 81
#define MSZ 80
#define NEL (M1 * M1)          // 6561
#define NTW ((NEL + 31) / 32)  // 206 words of target bits
#define NACC 12
#define BIGKC 1.0e30f
#define LOG81 4.394449154672439f
#define INV81 0.012345679012345678f

// accumulator indices:
// 0 target_num, 1 n_pre, 2 n_next, 3 n_union,
// 4 s_pre, 5 s_next, 6 s_all, 7 s_sim,
// 8 s_acc_pre, 9 s_acc_next, 10 n_mpre, 11 n_mnext

__global__ __launch_bounds__(512, 8) void sst_main(
    const float* __restrict__ input,
    const int* __restrict__ target,
    const int* __restrict__ mask0,
    const int* __restrict__ mask1,
    float* __restrict__ out_idx,   // d_out + 7, [slices*80] floats
    float* __restrict__ part,      // SoA: part[k*slices + slice]
    int slices)
{
    __shared__ float s_x[NEL];          // x during staging, z after sweep A
    __shared__ unsigned s_tb[NTW];      // target bits, row-major
    __shared__ float s_m0[M1], s_m1[M1];
    __shared__ float s_kc[M1];          // log(csum) (1e30 sentinel @80)
    __shared__ float s_invc[M1];        // 1/csum
    __shared__ float s_pA[486];         // sweepA csum partials
    __shared__ float s_pC[480];         // sweepB rsum partials
    __shared__ float s_pV[486];         // argmax value partials (A: col, C: row)
    __shared__ unsigned char s_pI[486]; // argmax index partials
    __shared__ unsigned char s_pT[486]; // first-target partials (127 = none)
    __shared__ unsigned s_m1w[4];       // m1 bitmask (bit c = mask1[c] != 0)
    __shared__ float s_wv[8][NACC];

    const int tid   = threadIdx.x;
    const int lane  = tid & 63;
    const int w     = tid >> 6;
    const int slice = blockIdx.x;
    const size_t base = (size_t)slice * NEL;

    if (tid < M1) s_m0[tid] = (float)mask0[slice * M1 + tid];
    else if (tid >= 128 && tid < 128 + M1) s_m1[tid - 128] = (float)mask1[slice * M1 + (tid - 128)];

    float a[NACC];
#pragma unroll
    for (int k = 0; k < NACC; ++k) a[k] = 0.0f;

    // ---- staging: coalesced input + ballot-packed target bits + target_num ----
    for (int i = tid; i < NEL; i += 512) {
        s_x[i] = input[base + i];
        const int tv = target[base + i];
        a[0] += (tv != 0) ? 1.0f : 0.0f;
        unsigned long long m = __ballot(tv != 0);
        if (lane == 0) {
            const int w2 = (i >> 5) & ~1;
            s_tb[w2] = (unsigned)m;
            if (w2 + 1 < NTW) s_tb[w2 + 1] = (unsigned)(m >> 32);
        }
    }
    __syncthreads();   // B1

    // m1 bit windows (consumed in sweep C, after B3)
    if (w == 0) {
        const unsigned long long m = __ballot(s_m1[lane] != 0.0f);
        if (lane == 0) { s_m1w[0] = (unsigned)m; s_m1w[1] = (unsigned)(m >> 32); }
    } else if (w == 1) {
        float v = 0.0f;
        if (lane < 17) v = s_m1[64 + lane];
        const unsigned long long m = __ballot(v != 0.0f);
        if (lane == 0) { s_m1w[2] = (unsigned)m; s_m1w[3] = 0u; }
    }

    // ---- sweep A: columns (81 cols x 6 threads); store z = m1c*m0r*x in place ----
    if (tid < 486) {
        const int c = tid / 6, j = tid - 6 * (tid / 6);
        const int r0 = j * 13 + ((j < 3) ? j : 3);
        const int len = (j < 3) ? 14 : 13;
        const float m1c = s_m1[c];
        const float mcol = (c == MSZ) ? 0.0f : m1c;  // next-mask zeroes col 80
        float cs = 0.0f, bv = -1.0f;
        int bi = r0, ct = 127;
        for (int i = 0; i < len; ++i) {
            const int r = r0 + i;
            const int idx = r * M1 + c;
            const float m0r = s_m0[r];
            const float z = m1c * m0r * s_x[idx];
            const float e = __expf(z);
            s_x[idx] = z;                     // same-thread overwrite: race-free
            cs += e;
            if (e > bv) { bv = e; bi = r; }   // first-max (e-domain, ascending r)
            const unsigned tb = (s_tb[idx >> 5] >> (idx & 31)) & 1u;
            if (ct == 127 && tb != 0u && (mcol * m0r) != 0.0f) ct = r;
        }
        s_pA[tid] = cs; s_pV[tid] = bv;
        s_pI[tid] = (unsigned char)bi; s_pT[tid] = (unsigned char)ct;
    }
    __syncthreads();   // B2

    // ---- sweep B (rows 0..79, tids 0..479) | column merge (tids 480..511) ----
    if (tid < 480) {
        const int r = tid / 6, j = tid - 6 * (tid / 6);
        const int c0 = j * 13 + ((j < 3) ? j : 3);
        const int len = (j < 3) ? 14 : 13;
        const int rb = r * M1 + c0;
        float rs = 0.0f;
        for (int i = 0; i < len; ++i) rs += __expf(s_x[rb + i]);
        s_pC[tid] = rs;
    } else {
        const int u = tid - 480;
        for (int c = u; c < M1; c += 32) {
            if (c < MSZ) {
                const int b = 6 * c;
                float cs = 0.0f;
#pragma unroll
                for (int k = 0; k < 6; ++k) cs += s_pA[b + k];
                float bv = s_pV[b]; int bi = s_pI[b];
#pragma unroll
                for (int k = 1; k < 6; ++k) {
                    const float v = s_pV[b + k];
                    if (v > bv) { bv = v; bi = s_pI[b + k]; }  // ascending: first-max
                }
                int ct = 127;
#pragma unroll
                for (int k = 0; k < 6; ++k) ct = min(ct, (int)s_pT[b + k]);
                if (ct == 127) ct = 0;
                s_kc[c] = __logf(cs);
                s_invc[c] = 1.0f / cs;
                const float m1c = s_m1[c];
                a[9]  += (bi == ct) ? m1c : 0.0f;
                a[11] += m1c;
            } else {
                s_kc[c] = BIGKC; s_invc[c] = INV81;  // col-80 sentinel
            }
        }
    }
    __syncthreads();   // B3

    // ---- sweep C: rows 0..79 (tids 0..479) + row-80 next-terms (tids 480..485) ----
    if (tid < 480) {
        const int r = tid / 6, j = tid - 6 * (tid / 6);
        const int c0 = j * 13 + ((j < 3) ? j : 3);
        const int len = (j < 3) ? 14 : 13;
        const int rb = r * M1;
        const int pb = 6 * r;
        const float rs = s_pC[pb] + s_pC[pb + 1] + s_pC[pb + 2]
                       + s_pC[pb + 3] + s_pC[pb + 4] + s_pC[pb + 5];
        const float lr = __logf(rs), invr = 1.0f / rs;
        const float m0f = s_m0[r];

        // bit window: t & m1 & m0p over cols [c0, c0+len)
        const int bp = rb + c0;
        const unsigned long long tw64 =
            ((unsigned long long)s_tb[(bp >> 5) + 1] << 32) | s_tb[bp >> 5];
        const int mp0 = c0 >> 5;
        const unsigned long long mw64 =
            ((unsigned long long)s_m1w[mp0 + 1] << 32) | s_m1w[mp0];
        const unsigned lenmask = (1u << len) - 1u;
        unsigned wb = (unsigned)(tw64 >> (bp & 31)) & (unsigned)(mw64 >> (c0 & 31)) & lenmask;
        if (m0f == 0.0f) wb = 0u;

        const unsigned w3 = (j == 5) ? (wb & 0x0FFFu) : wb;  // drop c=80 bit
        a[1] += (float)__popc(wb);   // n_pre
        a[2] += (float)__popc(w3);   // n_next (rows<80 part)
        a[3] += (float)__popc(w3);   // n_union
        const int ti = wb ? (c0 + __ffs(wb) - 1) : 127;

        // unconditional: row argmax of log(input_all) = z - min(lr,kc)
        float bv = -3.402823466e38f; int bi = c0;
        for (int i = 0; i < len; ++i) {
            const int c = c0 + i;
            const float val = s_x[rb + c] - fminf(lr, s_kc[c]);
            if (val > bv) { bv = val; bi = c; }   // strict >, ascending: first-max
        }
        // sparse t-terms
        unsigned wl = wb;
        while (wl) {
            const int b = __ffs(wl) - 1; wl &= wl - 1u;
            const int c = c0 + b;
            const float z = s_x[rb + c];
            const float kc = s_kc[c];
            a[4] += lr - z;                              // s_pre
            a[6] += fminf(lr, kc) - z;                   // s_all (c=80: min=lr)
            const bool c80 = (c == MSZ);
            a[5] += c80 ? 0.0f : (kc - z);               // s_next (rows<80 part)
            const float e = c80 ? 0.0f : __expf(z);
            a[7] = fmaf(e, fabsf(s_invc[c] - invr), a[7]);  // sim (union excl c80)
        }
        s_pV[tid] = bv; s_pI[tid] = (unsigned char)bi; s_pT[tid] = (unsigned char)ti;
    } else if (tid < 486) {
        // row 80: only n_next / s_next terms survive (next-mask keeps row 80)
        const int j = tid - 480;
        const int c0 = j * 13 + ((j < 3) ? j : 3);
        const int len = (j < 3) ? 14 : 13;
        const int rb = MSZ * M1;
        const float m80 = s_m0[MSZ];
        const int bp = rb + c0;
        const unsigned long long tw64 =
            ((unsigned long long)s_tb[(bp >> 5) + 1] << 32) | s_tb[bp >> 5];
        const int mp0 = c0 >> 5;
        const unsigned long long mw64 =
            ((unsigned long long)s_m1w[mp0 + 1] << 32) | s_m1w[mp0];
        const unsigned lenmask = (1u << len) - 1u;
        unsigned wb = (unsigned)(tw64 >> (bp & 31)) & (unsigned)(mw64 >> (c0 & 31)) & lenmask;
        if (m80 == 0.0f) wb = 0u;
        if (j == 5) wb &= 0x0FFFu;                       // next-mask zeroes col 80
        a[2] += (float)__popc(wb);
        while (wb) {
            const int b = __ffs(wb) - 1; wb &= wb - 1u;
            const int c = c0 + b;
            a[5] += s_kc[c] - s_x[rb + c];
        }
    }
    __syncthreads();   // B4

    if (tid < MSZ) {   // merge row argmax + accuracy_pre
        const int b = 6 * tid;
        float bv = s_pV[b]; int bi = s_pI[b];
#pragma unroll
        for (int k = 1; k < 6; ++k) {
            const float v = s_pV[b + k];
            if (v > bv) { bv = v; bi = s_pI[b + k]; }
        }
        int ti = 127;
#pragma unroll
        for (int k = 0; k < 6; ++k) ti = min(ti, (int)s_pT[b + k]);
        if (ti == 127) ti = 0;
        out_idx[(size_t)slice * MSZ + tid] = (float)bi;
        const float m0f = s_m0[tid];
        a[8]  += (bi == ti) ? m0f : 0.0f;
        a[10] += m0f;
    }

    // ---- block reduce: wave shuffle -> LDS -> SoA partials ----
#pragma unroll
    for (int k = 0; k < NACC; ++k) {
        float v = a[k];
        for (int off = 32; off > 0; off >>= 1) v += __shfl_down(v, off);
        if (lane == 0) s_wv[w][k] = v;
    }
    __syncthreads();   // B5
    if (tid < NACC) {
        float s = 0.0f;
#pragma unroll
        for (int ww = 0; ww < 8; ++ww) s += s_wv[ww][tid];
        part[(size_t)tid * slices + slice] = s;
    }
}

__global__ __launch_bounds__(256) void sst_final(
    const float* __restrict__ part, int slices, float* __restrict__ out)
{
    __shared__ double s_part[4][NACC];
    const int tid = threadIdx.x;
    double l[NACC];
#pragma unroll
    for (int k = 0; k < NACC; ++k) l[k] = 0.0;
    for (int s = tid; s < slices; s += 256) {
#pragma unroll
        for (int k = 0; k < NACC; ++k) l[k] += (double)part[(size_t)k * slices + s];
    }
#pragma unroll
    for (int k = 0; k < NACC; ++k) {
        double v = l[k];
        for (int off = 32; off > 0; off >>= 1) v += __shfl_down(v, off);
        if ((tid & 63) == 0) s_part[tid >> 6][k] = v;
    }
    __syncthreads();
    if (tid == 0) {
        double g[NACC];
#pragma unroll
        for (int k = 0; k < NACC; ++k)
            g[k] = s_part[0][k] + s_part[1][k] + s_part[2][k] + s_part[3][k];
        const double tnum = g[0], npre = g[1], nnext = g[2], nunion = g[3];
        const double spre = g[4], snext = g[5], sall = g[6], ssim = g[7];
        const double accp = g[8], accn = g[9], nmp = g[10], nmn = g[11];
        const double loss_pre  = (npre > 0.0) ? spre / npre : spre;
        const double loss_next = (nnext > 0.0) ? snext / nnext : snext;
        const double loss      = (npre > 0.0 && nnext > 0.0) ? sall / npre : sall;
        const double loss_sim  = (nunion > 0.0) ? ssim / tnum : ssim;
        const double total = (loss_pre + loss_next + loss + loss_sim) * 0.25;
        const double ap = (nmp > 0.0) ? accp / nmp : accp + 1.0;
        const double an = (nmn > 0.0) ? accn / nmn : accn + 1.0;
        out[0] = (float)loss_pre;
        out[1] = (float)loss_next;
        out[2] = (float)loss_sim;
        out[3] = (float)total;
        out[4] = (float)ap;
        out[5] = (float)an;
        out[6] = (float)((ap + an) * 0.5);
    }
}

extern "C" void kernel_launch(void* const* d_in, const int* in_sizes, int n_in,
                              void* d_out, int out_size, void* d_ws, size_t ws_size,
                              hipStream_t stream) {
    const float* input  = (const float*)d_in[0];
    const int*   target = (const int*)d_in[1];
    const int*   mask0  = (const int*)d_in[2];
    const int*   mask1  = (const int*)d_in[3];
    float* out = (float*)d_out;
    float* part = (float*)d_ws;   // NACC * slices floats, SoA

    const int slices = in_sizes[0] / NEL;  // B*C = 2048

    sst_main<<<slices, 512, 0, stream>>>(input, target, mask0, mask1, out + 7, part, slices);
    sst_final<<<1, 256, 0, stream>>>(part, slices, out);
}